// Round 4
// baseline (182.944 us; speedup 1.0000x reference)
//
#include <hip/hip_runtime.h>
#include <hip/hip_bf16.h>
#include <math.h>

typedef unsigned short u16;
typedef unsigned char u8;
typedef unsigned int u32;
typedef long long i64;
typedef __attribute__((ext_vector_type(4))) float f32x4;

// -------------------------------------------------- fp32 -> fp8 e4m3 (x16 pre-scale)
// l2-normed inputs: |x| <~ 0.3 -> x*16 in [~0.01, 4.8]: full mantissa, no saturation.
// Dequant folded into gemm epilogue (divide by 256*temp).
//
// K-PERMUTED OUTPUT: within each 128-byte K-block, byte (32s + 8f + b) of the
// logical row is stored at (32f + 8s + b)  [s,f in 0..3, b in 0..7]. Applied to
// BOTH A and B -> dot products unchanged (R9-verified technique). This makes a
// lane's two MFMA sub-step operands contiguous 16B chunks in LDS (B) and in
// GLOBAL (A reads chunk 2fq+sp directly).
__global__ void cvt_fused(const float* __restrict__ F, const float* __restrict__ T,
                          u32* __restrict__ Fb, u32* __restrict__ Tb,
                          float* __restrict__ out) {
    const int idx = blockIdx.x * blockDim.x + threadIdx.x;
    if (idx == 0) out[0] = 0.f;
    const float* s;
    u32* d;
    int i;
    if (idx < 65536) { s = F; d = Fb; i = idx; }
    else             { s = T; d = Tb; i = idx - 65536; }
    const float4 v0 = *(const float4*)(s + (size_t)i * 8);
    const float4 v1 = *(const float4*)(s + (size_t)i * 8 + 4);
    int lo = __builtin_amdgcn_cvt_pk_fp8_f32(v0.x * 16.f, v0.y * 16.f, 0, false);
    lo     = __builtin_amdgcn_cvt_pk_fp8_f32(v0.z * 16.f, v0.w * 16.f, lo, true);
    int hi = __builtin_amdgcn_cvt_pk_fp8_f32(v1.x * 16.f, v1.y * 16.f, 0, false);
    hi     = __builtin_amdgcn_cvt_pk_fp8_f32(v1.z * 16.f, v1.w * 16.f, hi, true);
    uint2 o; o.x = (u32)lo; o.y = (u32)hi;
    // permuted destination: row r, in-row byte o -> (t<<7)|(f<<5)|(s<<3)
    const int r  = i >> 6;                 // 64 8-byte groups per 512-elem row
    const int ob = (i & 63) << 3;          // in-row byte offset (multiple of 8)
    const int t  = ob >> 7;
    const int ss = (ob >> 5) & 3;
    const int f  = (ob >> 3) & 3;
    const int o2 = (t << 7) | (f << 5) | (ss << 3);
    ((uint2*)d)[r * 64 + (o2 >> 3)] = o;
}

// ---------------------------------------------------------------- GEMM + max
#define GLB_AS __attribute__((address_space(1)))
#define LDS_AS __attribute__((address_space(3)))

__device__ __forceinline__ void gload_lds16(const void* g, void* l) {
    __builtin_amdgcn_global_load_lds((const GLB_AS void*)g, (LDS_AS void*)l, 16, 0, 0);
}

__device__ __forceinline__ i64 half0(int4 v) { int2 p; p.x = v.x; p.y = v.y; return __builtin_bit_cast(i64, p); }
__device__ __forceinline__ i64 half1(int4 v) { int2 p; p.x = v.z; p.y = v.w; return __builtin_bit_cast(i64, p); }

// A: F fp8 [1024 x 512], B: T fp8 [32768 x 512] (row-major, K-permuted per cvt).
// sim[i*1024+j] = max_{q<32} dot(A[i],B[j*32+q]) / (256*temp)
//
// R14: A DIRECT FROM GLOBAL (L2/L1-resident), B in LDS, R12's proven
// 2-barrier loop. Post-mortem R11/R13: explicit pipelining at reduced
// occupancy loses; R12's 35 us ~= MFMA floor (16.6) + LDS floor (15) --
// the pipes serialize at barriers. Lever = REMOVE LDS traffic:
//  - A tile is 64 KB, L2-resident, shared by all bn blocks (and the 4
//    resident blocks/CU share bm in a dispatch generation -> L1 hits).
//    The cvt K-permutation makes a lane's A-fragment a contiguous 16B
//    global chunk (2fq+sp of its row) -- the LDS XOR swizzle cancels out.
//  - LDS traffic/CU halves (3 MB -> 1.5 MB); stage drain halves (4 glds).
//  - LDS 32 -> 16 KB; occupancy stays 4 blocks/CU (16 waves).
//  - A-loads issued BEFORE stage+barrier: their L2 latency hides under the
//    glds drain. aF (32 VGPR) live across barrier: ~115 total < 128 cap.
//  - XCD bn-slab kept (2 MB B-slab/XCD L2-resident, re-read 8x).
//
// LDS (B): row-major 128-B rows; 16B chunk c of row r stored at slot c^(r&7)
// (R4/R9-verified conflict-free). With the cvt K-permutation, lane (frow,fq)
// reads chunks {2fq, 2fq+1}: b128 #0 = sub-steps s0,s1 (dwords 01|23), #1 = s2,s3.
__global__ __launch_bounds__(256, 4)
void gemm_max(const u8* __restrict__ A, const u8* __restrict__ B,
              const float* __restrict__ temp_ptr, float* __restrict__ sim) {
    __shared__ __align__(16) u8 lB[128 * 128];   // 16 KB
    const int bid = blockIdx.x;                  // 0..2047
    const int bn  = ((bid & 7) << 5) | ((bid >> 3) & 31);  // XCD slab: xcd*32 + local
    const int bm  = bid >> 8;                               // 0..7, inner sweep
    const int tid  = threadIdx.x;
    const int wave = tid >> 6;
    const int lane = tid & 63;
    const int wm = wave >> 1;       // 0..1: rows wm*64
    const int wn = wave & 1;        // 0..1: cols wn*64

    f32x4 acc[4][4] = {};           // 64 VGPRs

    // B staging: one glds = 8 rows x 128B. lane -> srow = lane>>3, slot chunk
    // l&7 holds global chunk (l&7)^srow.
    const int srow = lane >> 3;
    const int aoff = srow * 512 + (((lane & 7) ^ srow) << 4);   // per-lane global offset
    const u8* gB = B + (size_t)(bn * 128) * 512 + aoff;         // + grp*4096 + k0

    const int frow = lane & 15;
    const int fq   = lane >> 4;
    const int r7   = frow & 7;

    // A fragment base: row bm*128 + wm*64 + frow, chunk 2fq (+sp)
    const u8* gAf = A + (size_t)(bm * 128 + wm * 64 + frow) * 512 + (fq << 5);

    for (int k0 = 0; k0 < 512; k0 += 128) {
        // A fragments straight from global (L1/L2): issued first so their
        // latency overlaps the glds drain at the barrier.
        int4 aF[2][4];
#pragma unroll
        for (int sp = 0; sp < 2; ++sp)
#pragma unroll
            for (int mt = 0; mt < 4; ++mt)
                aF[sp][mt] = *(const int4*)(gAf + (size_t)mt * 8192 + k0 + sp * 16);

        // B: 16 groups of 8 rows; this wave stages groups wave+4g.
#pragma unroll
        for (int g = 0; g < 4; ++g)
            gload_lds16(gB + (wave + 4 * g) * 4096 + k0, lB + (wave + 4 * g) * 1024);
        __syncthreads();

#pragma unroll
        for (int sp = 0; sp < 2; ++sp) {
            const int coff = (((fq << 1) + sp) ^ r7) << 4;
            int4 bF[4];
#pragma unroll
            for (int nt = 0; nt < 4; ++nt)
                bF[nt] = *(const int4*)&lB[(wn * 64 + nt * 16 + frow) * 128 + coff];
#pragma unroll
            for (int mt = 0; mt < 4; ++mt)
#pragma unroll
                for (int nt = 0; nt < 4; ++nt) {
                    acc[mt][nt] = __builtin_amdgcn_mfma_f32_16x16x32_fp8_fp8(
                        half0(aF[sp][mt]), half0(bF[nt]), acc[mt][nt], 0, 0, 0);
                    acc[mt][nt] = __builtin_amdgcn_mfma_f32_16x16x32_fp8_fp8(
                        half1(aF[sp][mt]), half1(bF[nt]), acc[mt][nt], 0, 0, 0);
                }
        }
        __syncthreads();
    }

    // epilogue: C row = bm*128 + wm*64 + mt*16 + fq*4 + rr ;
    //           col   = bn*128 + wn*64 + nt*16 + (l&15);  j = col>>5
    const float inv = 1.0f / (256.0f * (*temp_ptr));
    const int jb = (bn * 128 + wn * 64) >> 5;
#pragma unroll
    for (int mt = 0; mt < 4; ++mt) {
#pragma unroll
        for (int rr = 0; rr < 4; ++rr) {
            float v0 = fmaxf(acc[mt][0][rr], acc[mt][1][rr]);
            float v1 = fmaxf(acc[mt][2][rr], acc[mt][3][rr]);
#pragma unroll
            for (int off = 1; off < 16; off <<= 1) {
                v0 = fmaxf(v0, __shfl_xor(v0, off));
                v1 = fmaxf(v1, __shfl_xor(v1, off));
            }
            if ((lane & 15) == 0) {
                const int row = bm * 128 + wm * 64 + mt * 16 + fq * 4 + rr;
                sim[row * 1024 + jb]     = v0 * inv;
                sim[row * 1024 + jb + 1] = v1 * inv;
            }
        }
    }
}

// ---------------------------------------------------------------- per-row loss
// ONE WAVE PER ROW, zero LDS, zero barriers. Row (1024 fp32) in 16 regs/lane.
__device__ __forceinline__ u32 f2key(float x) {
    u32 b = __float_as_uint(x);
    return (b & 0x80000000u) ? ~b : (b | 0x80000000u);
}
__device__ __forceinline__ float key2f(u32 k) {
    return __uint_as_float((k & 0x80000000u) ? (k & 0x7fffffffu) : ~k);
}

__global__ __launch_bounds__(256)
void row_loss(const float* __restrict__ sim, float* __restrict__ out) {
    const int tid = threadIdx.x;
    const int lane = tid & 63;
    const int wv = tid >> 6;
    const int i = blockIdx.x * 4 + wv;          // row index

    float v[16];
    const float4* rp = (const float4*)(sim + (size_t)i * 1024);
#pragma unroll
    for (int t = 0; t < 4; ++t) {
        float4 f = rp[t * 64 + lane];
        v[t * 4 + 0] = f.x; v[t * 4 + 1] = f.y; v[t * 4 + 2] = f.z; v[t * 4 + 3] = f.w;
    }

    const int dslot = ((i >> 8) << 2) | (i & 3);
    const int dlane = (i >> 2) & 63;

    u32 k[16];
#pragma unroll
    for (int t = 0; t < 16; ++t) {
        u32 kk = f2key(v[t]);
        k[t] = (lane == dlane && t == dslot) ? 0u : kk;   // diag -> below any finite key
    }

    float pv = 0.f;
#pragma unroll
    for (int t = 0; t < 16; ++t) if (t == dslot) pv = v[t];
    const float pos = __shfl(pv, dlane);

    float m = v[0];
#pragma unroll
    for (int t = 1; t < 16; ++t) m = fmaxf(m, v[t]);
#pragma unroll
    for (int off = 32; off > 0; off >>= 1) m = fmaxf(m, __shfl_xor(m, off));
    float s = 0.f;
#pragma unroll
    for (int t = 0; t < 16; ++t) s += __expf(v[t] - m);
#pragma unroll
    for (int off = 32; off > 0; off >>= 1) s += __shfl_xor(s, off);
    const float loss_std = m + __logf(s) - pos;

    // binary search: largest x with count(key >= x) >= 512
    u32 lo = 0u, hi = 0xFFFFFFFFu;
    while (lo < hi) {
        const u32 span = hi - lo;
        const u32 mid = lo + (span >> 1) + (span & 1u);
        int cnt = 0;
#pragma unroll
        for (int t = 0; t < 16; ++t) cnt += (k[t] >= mid);
#pragma unroll
        for (int off = 32; off > 0; off >>= 1) cnt += __shfl_xor(cnt, off);
        if (cnt >= 512) lo = mid; else hi = mid - 1;
    }
    const u32 t_key = lo;
    const float tval = key2f(t_key);

    float se = 0.f;
    int cgt = 0;
#pragma unroll
    for (int t = 0; t < 16; ++t) {
        if (k[t] > t_key) { se += __expf(v[t] - m); ++cgt; }
    }
#pragma unroll
    for (int off = 32; off > 0; off >>= 1) se += __shfl_xor(se, off);
#pragma unroll
    for (int off = 32; off > 0; off >>= 1) cgt += __shfl_xor(cgt, off);

    const float sh = se + (float)(512 - cgt) * __expf(tval - m) + __expf(pos - m);
    const float hard = m + __logf(sh) - pos;

    if (lane == 0)
        atomicAdd(out, (loss_std + 0.5f * hard) * (1.0f / 1024.0f));
}

// ---------------------------------------------------------------- launch
extern "C" void kernel_launch(void* const* d_in, const int* in_sizes, int n_in,
                              void* d_out, int out_size, void* d_ws, size_t ws_size,
                              hipStream_t stream) {
    const float* F    = (const float*)d_in[0];   // 1024*512
    const float* T    = (const float*)d_in[1];   // 1024*32*512
    const float* temp = (const float*)d_in[2];   // scalar
    float* out = (float*)d_out;

    char* ws = (char*)d_ws;
    u32*  Fb8 = (u32*)ws;                                   // 0.5 MB fp8
    u32*  Tb8 = (u32*)(ws + (1u << 20));                    // 16 MB fp8
    float* sim = (float*)(ws + (1u << 20) + (32u << 20));   // 4 MB

    cvt_fused<<<8448, 256, 0, stream>>>(F, T, Fb8, Tb8, out);

    gemm_max<<<2048, 256, 0, stream>>>((const u8*)Fb8, (const u8*)Tb8, temp, sim);

    row_loss<<<256, 256, 0, stream>>>(sim, out);
}

// Round 5
// 155.877 us; speedup vs baseline: 1.1736x; 1.1736x over previous
//
#include <hip/hip_runtime.h>
#include <hip/hip_bf16.h>
#include <math.h>

typedef unsigned short u16;
typedef unsigned char u8;
typedef unsigned int u32;
typedef long long i64;
typedef __attribute__((ext_vector_type(4))) float f32x4;

// -------------------------------------------------- fp32 -> fp8 e4m3 (x16 pre-scale)
// l2-normed inputs: |x| <~ 0.3 -> x*16 in [~0.01, 4.8]: full mantissa, no saturation.
// Dequant folded into gemm epilogue (divide by 256*temp).
//
// K-PERMUTED OUTPUT: within each 128-byte K-block, byte (32s + 8f + b) of the
// logical row is stored at (32f + 8s + b)  [s,f in 0..3, b in 0..7]. Applied to
// BOTH A and B -> dot products unchanged (R9-verified technique). Makes a
// lane's MFMA sub-step operands contiguous 16B chunks; sub-steps {0,1} are the
// EVEN chunks, {2,3} the ODD chunks -> enables K=64-granular staging (R15).
__global__ void cvt_fused(const float* __restrict__ F, const float* __restrict__ T,
                          u32* __restrict__ Fb, u32* __restrict__ Tb,
                          float* __restrict__ out) {
    const int idx = blockIdx.x * blockDim.x + threadIdx.x;
    if (idx == 0) out[0] = 0.f;
    const float* s;
    u32* d;
    int i;
    if (idx < 65536) { s = F; d = Fb; i = idx; }
    else             { s = T; d = Tb; i = idx - 65536; }
    const float4 v0 = *(const float4*)(s + (size_t)i * 8);
    const float4 v1 = *(const float4*)(s + (size_t)i * 8 + 4);
    int lo = __builtin_amdgcn_cvt_pk_fp8_f32(v0.x * 16.f, v0.y * 16.f, 0, false);
    lo     = __builtin_amdgcn_cvt_pk_fp8_f32(v0.z * 16.f, v0.w * 16.f, lo, true);
    int hi = __builtin_amdgcn_cvt_pk_fp8_f32(v1.x * 16.f, v1.y * 16.f, 0, false);
    hi     = __builtin_amdgcn_cvt_pk_fp8_f32(v1.z * 16.f, v1.w * 16.f, hi, true);
    uint2 o; o.x = (u32)lo; o.y = (u32)hi;
    // permuted destination: row r, in-row byte o -> (t<<7)|(f<<5)|(s<<3)
    const int r  = i >> 6;                 // 64 8-byte groups per 512-elem row
    const int ob = (i & 63) << 3;          // in-row byte offset (multiple of 8)
    const int t  = ob >> 7;
    const int ss = (ob >> 5) & 3;
    const int f  = (ob >> 3) & 3;
    const int o2 = (t << 7) | (f << 5) | (ss << 3);
    ((uint2*)d)[r * 64 + (o2 >> 3)] = o;
}

// ---------------------------------------------------------------- GEMM + max
#define GLB_AS __attribute__((address_space(1)))
#define LDS_AS __attribute__((address_space(3)))

__device__ __forceinline__ void gload_lds16(const void* g, void* l) {
    __builtin_amdgcn_global_load_lds((const GLB_AS void*)g, (LDS_AS void*)l, 16, 0, 0);
}

__device__ __forceinline__ i64 half0(int4 v) { int2 p; p.x = v.x; p.y = v.y; return __builtin_bit_cast(i64, p); }
__device__ __forceinline__ i64 half1(int4 v) { int2 p; p.x = v.z; p.y = v.w; return __builtin_bit_cast(i64, p); }

// A: F fp8 [1024 x 512], B: T fp8 [32768 x 512] (row-major, K-permuted per cvt).
// sim[i*1024+j] = max_{q<32} dot(A[i],B[j*32+q]) / (256*temp)
//
// R15: DOUBLE-BUFFER AT FULL OCCUPANCY via BK=64.
// Post-mortems: R12 (35us) = MFMA floor 16.6 + LDS ~14, serialized by the
// per-K-step vmcnt(0) drain; R11/R13 proved occupancy (4 blk/CU) > pipelining;
// R14 proved the 128-unified-VGPR cap (acc 64 -> only ~30 spare long-lived regs).
// BK=64 halves the buffer: 2 x (8KB A + 8KB B) = 32 KB -> dbuf AND 4 blk/CU.
// R11's single-__syncthreads pipeline: prefetch(t+1) issued right after the
// barrier, drained at the NEXT barrier (one compute-phase later -> latency
// hidden); barrier's own lgkmcnt(0) fences write-after-read. Fragments stay
// LDS-sourced, short-lived -> no spill.
//
// K-half staging under the cvt permutation: sub-steps {0,1} of a 128B K-block
// are its EVEN 16B chunks, {2,3} the ODD ones. glds sources are per-lane:
// lane l covers pair-row l>>3, slot l&7; u=(l&7)^(l>>3) -> row parity u>>2,
// fq' = u&3; src = (2*(l>>3)+(u>>2))*512 + 32*(u&3) + kterm, one glds = 16
// rows. kterm(t) = 128*(t>>1) + 16*(t&1). Read: one b128 per tile at pair-row
// wm*32+mt*8+(frow>>1), slot (4*(frow&1)+fq)^(frow>>1) -- same 8-slot x 8-lane
// distribution as the R4/R9-verified layout (conflict-free); XOR keys match
// write side. K order per acc unchanged (ss 0,1,2,3) -> bit-exact vs R12.
__global__ __launch_bounds__(256, 4)
void gemm_max(const u8* __restrict__ A, const u8* __restrict__ B,
              const float* __restrict__ temp_ptr, float* __restrict__ sim) {
    __shared__ __align__(16) u8 lA[2][128 * 64];   // 2 x 8 KB (128 rows x 64B half-K)
    __shared__ __align__(16) u8 lB[2][128 * 64];   // 2 x 8 KB
    const int bid = blockIdx.x;                  // 0..2047
    const int bn  = ((bid & 7) << 5) | ((bid >> 3) & 31);  // XCD slab: xcd*32 + local
    const int bm  = bid >> 8;                               // 0..7, inner sweep
    const int tid  = threadIdx.x;
    const int wave = tid >> 6;
    const int lane = tid & 63;
    const int wm = wave >> 1;       // 0..1: rows wm*64
    const int wn = wave & 1;        // 0..1: cols wn*64

    f32x4 acc[4][4] = {};           // 64 VGPRs

    // staging lane constants: one glds = 16 rows (8 pair-rows x 8 slots)
    const int pl   = lane >> 3;          // pair-row in group (0..7)
    const int sl   = lane & 7;           // slot (0..7)
    const int uu   = sl ^ pl;            // unswizzled selector
    const int stoff = (2 * pl + (uu >> 2)) * 512 + ((uu & 3) << 5);  // per-lane src
    const u8* gA2 = A + (size_t)(bm * 128) * 512 + stoff;   // + grp*8192 + kterm
    const u8* gB2 = B + (size_t)(bn * 128) * 512 + stoff;

    const int frow = lane & 15;
    const int fq   = lane >> 4;
    // read-side: pair-row base + XOR slot (key = pair-row & 7 = frow>>1)
    const int prr  = frow >> 1;
    const int slotr = ((((frow & 1) << 2) + fq) ^ prr) << 4;   // byte offset
    const int prA = (wm * 32 + prr) * 128 + slotr;             // + mt*1024
    const int prB = (wn * 32 + prr) * 128 + slotr;             // + nt*1024

    // 4 glds per wave per k-step: A groups {wave, wave+4}, B groups {wave, wave+4}
#define STAGE(pb, t) do {                                                            \
        const int kt = 128 * ((t) >> 1) + 16 * ((t) & 1);                            \
        gload_lds16(gA2 + (wave)     * 8192 + kt, &lA[pb][(wave)     * 1024]);       \
        gload_lds16(gA2 + (wave + 4) * 8192 + kt, &lA[pb][(wave + 4) * 1024]);       \
        gload_lds16(gB2 + (wave)     * 8192 + kt, &lB[pb][(wave)     * 1024]);       \
        gload_lds16(gB2 + (wave + 4) * 8192 + kt, &lB[pb][(wave + 4) * 1024]);       \
    } while (0)

    STAGE(0, 0);
#pragma unroll
    for (int t = 0; t < 8; ++t) {
        __syncthreads();                       // drains stage(t); fences reads(t-1)
        if (t < 7) STAGE((t + 1) & 1, t + 1);  // prefetch, drained at next barrier
        const int pb = t & 1;

        int4 aF[4], bF[4];
#pragma unroll
        for (int mt = 0; mt < 4; ++mt)
            aF[mt] = *(const int4*)&lA[pb][prA + mt * 1024];
#pragma unroll
        for (int nt = 0; nt < 4; ++nt)
            bF[nt] = *(const int4*)&lB[pb][prB + nt * 1024];

        __builtin_amdgcn_s_setprio(1);
#pragma unroll
        for (int mt = 0; mt < 4; ++mt)
#pragma unroll
            for (int nt = 0; nt < 4; ++nt) {
                acc[mt][nt] = __builtin_amdgcn_mfma_f32_16x16x32_fp8_fp8(
                    half0(aF[mt]), half0(bF[nt]), acc[mt][nt], 0, 0, 0);
                acc[mt][nt] = __builtin_amdgcn_mfma_f32_16x16x32_fp8_fp8(
                    half1(aF[mt]), half1(bF[nt]), acc[mt][nt], 0, 0, 0);
            }
        __builtin_amdgcn_s_setprio(0);
    }
#undef STAGE

    // epilogue: C row = bm*128 + wm*64 + mt*16 + fq*4 + rr ;
    //           col   = bn*128 + wn*64 + nt*16 + (l&15);  j = col>>5
    const float inv = 1.0f / (256.0f * (*temp_ptr));
    const int jb = (bn * 128 + wn * 64) >> 5;
#pragma unroll
    for (int mt = 0; mt < 4; ++mt) {
#pragma unroll
        for (int rr = 0; rr < 4; ++rr) {
            float v0 = fmaxf(acc[mt][0][rr], acc[mt][1][rr]);
            float v1 = fmaxf(acc[mt][2][rr], acc[mt][3][rr]);
#pragma unroll
            for (int off = 1; off < 16; off <<= 1) {
                v0 = fmaxf(v0, __shfl_xor(v0, off));
                v1 = fmaxf(v1, __shfl_xor(v1, off));
            }
            if ((lane & 15) == 0) {
                const int row = bm * 128 + wm * 64 + mt * 16 + fq * 4 + rr;
                sim[row * 1024 + jb]     = v0 * inv;
                sim[row * 1024 + jb + 1] = v1 * inv;
            }
        }
    }
}

// ---------------------------------------------------------------- per-row loss
// ONE WAVE PER ROW, zero LDS, zero barriers. Row (1024 fp32) in 16 regs/lane.
__device__ __forceinline__ u32 f2key(float x) {
    u32 b = __float_as_uint(x);
    return (b & 0x80000000u) ? ~b : (b | 0x80000000u);
}
__device__ __forceinline__ float key2f(u32 k) {
    return __uint_as_float((k & 0x80000000u) ? (k & 0x7fffffffu) : ~k);
}

__global__ __launch_bounds__(256)
void row_loss(const float* __restrict__ sim, float* __restrict__ out) {
    const int tid = threadIdx.x;
    const int lane = tid & 63;
    const int wv = tid >> 6;
    const int i = blockIdx.x * 4 + wv;          // row index

    float v[16];
    const float4* rp = (const float4*)(sim + (size_t)i * 1024);
#pragma unroll
    for (int t = 0; t < 4; ++t) {
        float4 f = rp[t * 64 + lane];
        v[t * 4 + 0] = f.x; v[t * 4 + 1] = f.y; v[t * 4 + 2] = f.z; v[t * 4 + 3] = f.w;
    }

    const int dslot = ((i >> 8) << 2) | (i & 3);
    const int dlane = (i >> 2) & 63;

    u32 k[16];
#pragma unroll
    for (int t = 0; t < 16; ++t) {
        u32 kk = f2key(v[t]);
        k[t] = (lane == dlane && t == dslot) ? 0u : kk;   // diag -> below any finite key
    }

    float pv = 0.f;
#pragma unroll
    for (int t = 0; t < 16; ++t) if (t == dslot) pv = v[t];
    const float pos = __shfl(pv, dlane);

    float m = v[0];
#pragma unroll
    for (int t = 1; t < 16; ++t) m = fmaxf(m, v[t]);
#pragma unroll
    for (int off = 32; off > 0; off >>= 1) m = fmaxf(m, __shfl_xor(m, off));
    float s = 0.f;
#pragma unroll
    for (int t = 0; t < 16; ++t) s += __expf(v[t] - m);
#pragma unroll
    for (int off = 32; off > 0; off >>= 1) s += __shfl_xor(s, off);
    const float loss_std = m + __logf(s) - pos;

    // binary search: largest x with count(key >= x) >= 512
    u32 lo = 0u, hi = 0xFFFFFFFFu;
    while (lo < hi) {
        const u32 span = hi - lo;
        const u32 mid = lo + (span >> 1) + (span & 1u);
        int cnt = 0;
#pragma unroll
        for (int t = 0; t < 16; ++t) cnt += (k[t] >= mid);
#pragma unroll
        for (int off = 32; off > 0; off >>= 1) cnt += __shfl_xor(cnt, off);
        if (cnt >= 512) lo = mid; else hi = mid - 1;
    }
    const u32 t_key = lo;
    const float tval = key2f(t_key);

    float se = 0.f;
    int cgt = 0;
#pragma unroll
    for (int t = 0; t < 16; ++t) {
        if (k[t] > t_key) { se += __expf(v[t] - m); ++cgt; }
    }
#pragma unroll
    for (int off = 32; off > 0; off >>= 1) se += __shfl_xor(se, off);
#pragma unroll
    for (int off = 32; off > 0; off >>= 1) cgt += __shfl_xor(cgt, off);

    const float sh = se + (float)(512 - cgt) * __expf(tval - m) + __expf(pos - m);
    const float hard = m + __logf(sh) - pos;

    if (lane == 0)
        atomicAdd(out, (loss_std + 0.5f * hard) * (1.0f / 1024.0f));
}

// ---------------------------------------------------------------- launch
extern "C" void kernel_launch(void* const* d_in, const int* in_sizes, int n_in,
                              void* d_out, int out_size, void* d_ws, size_t ws_size,
                              hipStream_t stream) {
    const float* F    = (const float*)d_in[0];   // 1024*512
    const float* T    = (const float*)d_in[1];   // 1024*32*512
    const float* temp = (const float*)d_in[2];   // scalar
    float* out = (float*)d_out;

    char* ws = (char*)d_ws;
    u32*  Fb8 = (u32*)ws;                                   // 0.5 MB fp8
    u32*  Tb8 = (u32*)(ws + (1u << 20));                    // 16 MB fp8
    float* sim = (float*)(ws + (1u << 20) + (32u << 20));   // 4 MB

    cvt_fused<<<8448, 256, 0, stream>>>(F, T, Fb8, Tb8, out);

    gemm_max<<<2048, 256, 0, stream>>>((const u8*)Fb8, (const u8*)Tb8, temp, sim);

    row_loss<<<256, 256, 0, stream>>>(sim, out);
}

// Round 6
// 150.594 us; speedup vs baseline: 1.2148x; 1.0351x over previous
//
#include <hip/hip_runtime.h>
#include <hip/hip_bf16.h>
#include <math.h>

typedef unsigned short u16;
typedef unsigned char u8;
typedef unsigned int u32;
typedef long long i64;
typedef __attribute__((ext_vector_type(4))) float f32x4;
typedef __attribute__((ext_vector_type(4))) int   i32x4;

// -------------------------------------------------- fp32 -> int8 (x127 symmetric)
// l2-normed inputs: |x| <= 1 -> rint(x*127) in [-127,127]. EXACT i32 MFMA
// accumulation; dequant (1/(127^2*temp)) folded into gemm epilogue.
// Quant noise sigma_dot ~0.0032 (vs fp8's 0.0022); both loss terms are
// per-row shift-invariant so selection bias cancels.
//
// PLAIN ROW-MAJOR output: the i8 16x16x64 MFMA lane operand (k=16g+c) is a
// naturally contiguous 16B chunk of a row-major K-block -- the fp8-era
// K-permutation is unnecessary and deleted.
__global__ void cvt_fused(const float* __restrict__ F, const float* __restrict__ T,
                          u32* __restrict__ Fb, u32* __restrict__ Tb,
                          float* __restrict__ out) {
    const int idx = blockIdx.x * blockDim.x + threadIdx.x;
    if (idx == 0) out[0] = 0.f;
    const float* s;
    u32* d;
    int i;
    if (idx < 65536) { s = F; d = Fb; i = idx; }
    else             { s = T; d = Tb; i = idx - 65536; }
    const float4 v0 = *(const float4*)(s + (size_t)i * 8);
    const float4 v1 = *(const float4*)(s + (size_t)i * 8 + 4);
    const int q0 = __float2int_rn(v0.x * 127.f), q1 = __float2int_rn(v0.y * 127.f);
    const int q2 = __float2int_rn(v0.z * 127.f), q3 = __float2int_rn(v0.w * 127.f);
    const int q4 = __float2int_rn(v1.x * 127.f), q5 = __float2int_rn(v1.y * 127.f);
    const int q6 = __float2int_rn(v1.z * 127.f), q7 = __float2int_rn(v1.w * 127.f);
    uint2 o;
    o.x = (u32)(q0 & 255) | ((u32)(q1 & 255) << 8) | ((u32)(q2 & 255) << 16) | ((u32)(q3 & 255) << 24);
    o.y = (u32)(q4 & 255) | ((u32)(q5 & 255) << 8) | ((u32)(q6 & 255) << 16) | ((u32)(q7 & 255) << 24);
    ((uint2*)d)[i] = o;
}

// ---------------------------------------------------------------- GEMM + max
#define GLB_AS __attribute__((address_space(1)))
#define LDS_AS __attribute__((address_space(3)))

__device__ __forceinline__ void gload_lds16(const void* g, void* l) {
    __builtin_amdgcn_global_load_lds((const GLB_AS void*)g, (LDS_AS void*)l, 16, 0, 0);
}

// A: F i8 [1024 x 512], B: T i8 [32768 x 512] (row-major).
// sim[i*1024+j] = max_{q<32} dot(A[i],B[j*32+q]) / (127^2*temp)
//
// R16: i8 MFMA (16x16x64, ~3944 TOPS = 2x the non-scaled fp8 rate, m16).
// Post-mortems R11/R13/R15: ALL scheduling attacks on R12's 2-barrier loop
// are neutral-to-negative -- ~35us is pipe-demand-bound (MFMA 16.5 + LDS
// ~13), not drain-bound. So SHRINK A PIPE: i8 K=64 halves MFMA cycles at
// identical operand bytes / register footprint / LDS traffic, keeping the
// proven structure: BK=128 single-buffer 32 KB, 4 blk/CU, XCD bn-slab.
// i32 accumulation is exact (|dot| <= 512*127^2 ~ 8.3e6 << 2^31).
//
// LDS: row-major 128-B rows; 16B chunk c of row r at slot c^(r&7)
// (R4/R9-verified). Lane (frow,fq), sub-instr h reads chunk 4h+fq ->
// slot (4h+fq)^r7: per quarter-wave 8 slots x 2 rows = benign 2-way.
__global__ __launch_bounds__(256, 4)
void gemm_max(const u8* __restrict__ A, const u8* __restrict__ B,
              const float* __restrict__ temp_ptr, float* __restrict__ sim) {
    __shared__ __align__(16) u8 lA[128 * 128];   // 16 KB
    __shared__ __align__(16) u8 lB[128 * 128];   // 16 KB
    const int bid = blockIdx.x;                  // 0..2047
    const int bn  = ((bid & 7) << 5) | ((bid >> 3) & 31);  // XCD slab: xcd*32 + local
    const int bm  = bid >> 8;                               // 0..7, inner sweep
    const int tid  = threadIdx.x;
    const int wave = tid >> 6;
    const int lane = tid & 63;
    const int wm = wave >> 1;       // 0..1: rows wm*64
    const int wn = wave & 1;        // 0..1: cols wn*64

    i32x4 acc[4][4] = {};           // 64 VGPRs, exact i32

    // staging: one glds = 8 rows x 128B. lane -> srow = lane>>3, slot chunk
    // l&7 holds global chunk (l&7)^srow.
    const int srow = lane >> 3;
    const int aoff = srow * 512 + (((lane & 7) ^ srow) << 4);   // per-lane global offset
    const u8* gA = A + (size_t)(bm * 128) * 512 + aoff;         // + grp*4096 + k0
    const u8* gB = B + (size_t)(bn * 128) * 512 + aoff;         // + grp*4096 + k0

    const int frow = lane & 15;
    const int fq   = lane >> 4;
    const int r7   = frow & 7;

    for (int k0 = 0; k0 < 512; k0 += 128) {
        // A and B each: 16 groups of 8 rows; this wave stages groups wave+4g.
#pragma unroll
        for (int g = 0; g < 4; ++g)
            gload_lds16(gA + (wave + 4 * g) * 4096 + k0, lA + (wave + 4 * g) * 1024);
#pragma unroll
        for (int g = 0; g < 4; ++g)
            gload_lds16(gB + (wave + 4 * g) * 4096 + k0, lB + (wave + 4 * g) * 1024);
        __syncthreads();

#pragma unroll
        for (int h = 0; h < 2; ++h) {           // K=64 halves of the 128-block
            const int coff = (((h << 2) + fq) ^ r7) << 4;
            i32x4 aF[4], bF[4];
#pragma unroll
            for (int mt = 0; mt < 4; ++mt)
                aF[mt] = *(const i32x4*)&lA[(wm * 64 + mt * 16 + frow) * 128 + coff];
#pragma unroll
            for (int nt = 0; nt < 4; ++nt)
                bF[nt] = *(const i32x4*)&lB[(wn * 64 + nt * 16 + frow) * 128 + coff];
#pragma unroll
            for (int mt = 0; mt < 4; ++mt)
#pragma unroll
                for (int nt = 0; nt < 4; ++nt)
                    acc[mt][nt] = __builtin_amdgcn_mfma_i32_16x16x64_i8(
                        aF[mt], bF[nt], acc[mt][nt], 0, 0, 0);
        }
        __syncthreads();
    }

    // epilogue: C row = bm*128 + wm*64 + mt*16 + fq*4 + rr ;
    //           col   = bn*128 + wn*64 + nt*16 + (l&15);  j = col>>5
    // int max is exact; convert once, then dequant.
    const float inv = 1.0f / (16129.0f * (*temp_ptr));
    const int jb = (bn * 128 + wn * 64) >> 5;
#pragma unroll
    for (int mt = 0; mt < 4; ++mt) {
#pragma unroll
        for (int rr = 0; rr < 4; ++rr) {
            int m0 = max(acc[mt][0][rr], acc[mt][1][rr]);
            int m1 = max(acc[mt][2][rr], acc[mt][3][rr]);
#pragma unroll
            for (int off = 1; off < 16; off <<= 1) {
                m0 = max(m0, __shfl_xor(m0, off));
                m1 = max(m1, __shfl_xor(m1, off));
            }
            if ((lane & 15) == 0) {
                const int row = bm * 128 + wm * 64 + mt * 16 + fq * 4 + rr;
                sim[row * 1024 + jb]     = (float)m0 * inv;
                sim[row * 1024 + jb + 1] = (float)m1 * inv;
            }
        }
    }
}

// ---------------------------------------------------------------- per-row loss
// ONE WAVE PER ROW, zero LDS, zero barriers. Row (1024 fp32) in 16 regs/lane.
__device__ __forceinline__ u32 f2key(float x) {
    u32 b = __float_as_uint(x);
    return (b & 0x80000000u) ? ~b : (b | 0x80000000u);
}
__device__ __forceinline__ float key2f(u32 k) {
    return __uint_as_float((k & 0x80000000u) ? (k & 0x7fffffffu) : ~k);
}

__global__ __launch_bounds__(256)
void row_loss(const float* __restrict__ sim, float* __restrict__ out) {
    const int tid = threadIdx.x;
    const int lane = tid & 63;
    const int wv = tid >> 6;
    const int i = blockIdx.x * 4 + wv;          // row index

    float v[16];
    const float4* rp = (const float4*)(sim + (size_t)i * 1024);
#pragma unroll
    for (int t = 0; t < 4; ++t) {
        float4 f = rp[t * 64 + lane];
        v[t * 4 + 0] = f.x; v[t * 4 + 1] = f.y; v[t * 4 + 2] = f.z; v[t * 4 + 3] = f.w;
    }

    const int dslot = ((i >> 8) << 2) | (i & 3);
    const int dlane = (i >> 2) & 63;

    u32 k[16];
#pragma unroll
    for (int t = 0; t < 16; ++t) {
        u32 kk = f2key(v[t]);
        k[t] = (lane == dlane && t == dslot) ? 0u : kk;   // diag -> below any finite key
    }

    float pv = 0.f;
#pragma unroll
    for (int t = 0; t < 16; ++t) if (t == dslot) pv = v[t];
    const float pos = __shfl(pv, dlane);

    float m = v[0];
#pragma unroll
    for (int t = 1; t < 16; ++t) m = fmaxf(m, v[t]);
#pragma unroll
    for (int off = 32; off > 0; off >>= 1) m = fmaxf(m, __shfl_xor(m, off));
    float s = 0.f;
#pragma unroll
    for (int t = 0; t < 16; ++t) s += __expf(v[t] - m);
#pragma unroll
    for (int off = 32; off > 0; off >>= 1) s += __shfl_xor(s, off);
    const float loss_std = m + __logf(s) - pos;

    // binary search: largest x with count(key >= x) >= 512
    u32 lo = 0u, hi = 0xFFFFFFFFu;
    while (lo < hi) {
        const u32 span = hi - lo;
        const u32 mid = lo + (span >> 1) + (span & 1u);
        int cnt = 0;
#pragma unroll
        for (int t = 0; t < 16; ++t) cnt += (k[t] >= mid);
#pragma unroll
        for (int off = 32; off > 0; off >>= 1) cnt += __shfl_xor(cnt, off);
        if (cnt >= 512) lo = mid; else hi = mid - 1;
    }
    const u32 t_key = lo;
    const float tval = key2f(t_key);

    float se = 0.f;
    int cgt = 0;
#pragma unroll
    for (int t = 0; t < 16; ++t) {
        if (k[t] > t_key) { se += __expf(v[t] - m); ++cgt; }
    }
#pragma unroll
    for (int off = 32; off > 0; off >>= 1) se += __shfl_xor(se, off);
#pragma unroll
    for (int off = 32; off > 0; off >>= 1) cgt += __shfl_xor(cgt, off);

    const float sh = se + (float)(512 - cgt) * __expf(tval - m) + __expf(pos - m);
    const float hard = m + __logf(sh) - pos;

    if (lane == 0)
        atomicAdd(out, (loss_std + 0.5f * hard) * (1.0f / 1024.0f));
}

// ---------------------------------------------------------------- launch
extern "C" void kernel_launch(void* const* d_in, const int* in_sizes, int n_in,
                              void* d_out, int out_size, void* d_ws, size_t ws_size,
                              hipStream_t stream) {
    const float* F    = (const float*)d_in[0];   // 1024*512
    const float* T    = (const float*)d_in[1];   // 1024*32*512
    const float* temp = (const float*)d_in[2];   // scalar
    float* out = (float*)d_out;

    char* ws = (char*)d_ws;
    u32*  Fb8 = (u32*)ws;                                   // 0.5 MB i8
    u32*  Tb8 = (u32*)(ws + (1u << 20));                    // 16 MB i8
    float* sim = (float*)(ws + (1u << 20) + (32u << 20));   // 4 MB

    cvt_fused<<<8448, 256, 0, stream>>>(F, T, Fb8, Tb8, out);

    gemm_max<<<2048, 256, 0, stream>>>((const u8*)Fb8, (const u8*)Tb8, temp, sim);

    row_loss<<<256, 256, 0, stream>>>(sim, out);
}